// Round 3
// baseline (2340.802 us; speedup 1.0000x reference)
//
#include <hip/hip_runtime.h>
#include <math.h>

// Problem constants
#define NB   128
#define NT   25
#define NCH  512
#define HL   256      // LSTM hidden per direction
#define NHW  256      // 8*32
#define NCLS 38

// ---------------- workspace layout (float offsets) ----------------
// Anorm lives whole run. Cpool dead after LSTM-input GEMMs -> hT/hgT alias it.
// lstm_out dead after GRU-x GEMM -> gru_out aliases it.
#define OFF_ANORM   0u
#define SZ_ANORM    (128u*25u*256u)              // 819200
#define OFF_CPOOL   (OFF_ANORM + SZ_ANORM)       // 819200
#define SZ_CPOOL    (25u*128u*512u)              // 1638400
#define OFF_HT      OFF_CPOOL                    // alias: 2dir*2buf*256*128 = 131072
#define OFF_HGT     (OFF_CPOOL + 131072u)        // alias: 2buf*512*128      = 131072
#define OFF_G       (OFF_CPOOL + SZ_CPOOL)       // 2457600
#define SZ_GF       (1024u*3200u)                // 3276800
#define OFF_GF      OFF_G
#define OFF_GB      (OFF_G + SZ_GF)
#define OFF_GX      OFF_G                        // alias: 1536*3200 <= 2*SZ_GF
#define OFF_LSTMOUT (OFF_G + 2u*SZ_GF)           // 9011200
#define SZ_LSTMOUT  (25u*128u*512u)              // 1638400
#define OFF_GRUOUT  OFF_LSTMOUT                  // alias: lstm_out dead when gru writes
#define OFF_EMBTAB  (OFF_LSTMOUT + SZ_LSTMOUT)   // 10649600
#define SZ_EMBTAB   (38u*1536u)                  // 58368
#define OFF_INT     (OFF_EMBTAB + SZ_EMBTAB)     // 10707968: [0..3]=cnt, [8..]=pfx
// total ~10.71M floats ~= 42.8 MB

__device__ __forceinline__ float sigm(float x) { return 1.0f / (1.0f + expf(-x)); }

// ---------------- grid barrier (agent scope, cross-XCD safe) ----------------
// Monotonic counter: each participating block adds 1 per step; wait for target.
// Release add publishes this block's writes (L2 writeback); acquire fence
// (L1/L2 invalidate) before re-reading. Same recipe as ROCm coop-groups.
__device__ __forceinline__ void gridbar(int* cnt, int target) {
    __syncthreads();
    if (threadIdx.x == 0) {
        __hip_atomic_fetch_add(cnt, 1, __ATOMIC_RELEASE, __HIP_MEMORY_SCOPE_AGENT);
        while (__hip_atomic_load(cnt, __ATOMIC_RELAXED, __HIP_MEMORY_SCOPE_AGENT) < target) {
            __builtin_amdgcn_s_sleep(2);
        }
        __builtin_amdgcn_fence(__ATOMIC_ACQUIRE, "agent");
    }
    __syncthreads();
}

// ---------------- prefix sums of text_length ----------------
__global__ void prefix_kernel(const int* __restrict__ tlen, int* __restrict__ pfx) {
    if (threadIdx.x == 0) {
        int s = 0;
        for (int i = 0; i < NB; ++i) { pfx[i] = s; s += tlen[i]; }
        pfx[NB] = s;
    }
}

// ---------------- normalize attention maps per (b,t) ----------------
__global__ __launch_bounds__(256) void norm_attn_kernel(const float* __restrict__ A,
                                                        float* __restrict__ An) {
    const int bt = blockIdx.x;             // b*25 + t
    const int tid = threadIdx.x;
    float v = A[(size_t)bt * NHW + tid];
    float s = v;
    #pragma unroll
    for (int off = 32; off > 0; off >>= 1) s += __shfl_down(s, off, 64);
    __shared__ float wsum[4];
    if ((tid & 63) == 0) wsum[tid >> 6] = s;
    __syncthreads();
    float tot = wsum[0] + wsum[1] + wsum[2] + wsum[3];
    An[(size_t)bt * NHW + tid] = v / tot;
}

// ---------------- attention-weighted pooling: Cpool[t][b][c] = sum_hw feat[b][c][hw]*An[b][t][hw]
__global__ __launch_bounds__(256) void pool_kernel(const float* __restrict__ feature,
                                                   const float* __restrict__ An,
                                                   float* __restrict__ Cpool) {
    __shared__ float al[25][256];          // 25.6 KB
    const int b = blockIdx.y;
    const int c = blockIdx.x * 256 + threadIdx.x;
    for (int i = threadIdx.x; i < 25 * 256; i += 256)
        al[i >> 8][i & 255] = An[(size_t)b * 25 * 256 + i];
    __syncthreads();
    const float* f = feature + ((size_t)b * NCH + c) * NHW;
    float acc[25];
    #pragma unroll
    for (int t = 0; t < 25; ++t) acc[t] = 0.f;
    for (int hw = 0; hw < NHW; hw += 4) {
        const float4 fv = *(const float4*)(f + hw);
        #pragma unroll
        for (int t = 0; t < 25; ++t) {
            const float4 av = *(const float4*)&al[t][hw];
            acc[t] += fv.x * av.x + fv.y * av.y + fv.z * av.z + fv.w * av.w;
        }
    }
    #pragma unroll
    for (int t = 0; t < 25; ++t)
        Cpool[((size_t)t * NB + b) * NCH + c] = acc[t];
}

// ---------------- fp32 GEMM: C[m][n] = sum_k A[m][k]*B[n][k] (+bm1[m]+bm2[m]+bn[n])
// 128x128 tile, BK=16, 256 threads, 8x8 acc/thread in 4 quadrants:
// rows {ty*4+r, 64+ty*4+r}, cols {tx*4+c, 64+tx*4+c}.
// Bank audit: A-reads 4-addr broadcast (free); B-reads tx*4 -> 2-way (free);
// staging writes 2-way (free). 64 indep FMAs per 4 ds_read_b128.
__global__ __launch_bounds__(256) void gemm_tn_kernel(
    int M, int N, int K,
    const float* __restrict__ Amat, int lda,
    const float* __restrict__ Bmat, int ldb,
    const float* __restrict__ bm1, const float* __restrict__ bm2,
    const float* __restrict__ bnv,
    float* __restrict__ C, int ldc)
{
    __shared__ float As[16][128];
    __shared__ float Bs[16][128];
    const int tid = threadIdx.x;
    const int m0 = blockIdx.y * 128;
    const int n0 = blockIdx.x * 128;
    const int ty = tid >> 4, tx = tid & 15;
    const int srow = tid >> 1, scol = (tid & 1) * 8;   // staging: row, k-offset

    float acc[8][8];
    #pragma unroll
    for (int r = 0; r < 8; ++r)
        #pragma unroll
        for (int c = 0; c < 8; ++c) acc[r][c] = 0.f;

    for (int k0 = 0; k0 < K; k0 += 16) {
        float4 a0 = {0,0,0,0}, a1 = {0,0,0,0};
        if (m0 + srow < M) {
            const float* p = Amat + (size_t)(m0 + srow) * lda + k0 + scol;
            a0 = *(const float4*)p; a1 = *(const float4*)(p + 4);
        }
        float4 b0 = {0,0,0,0}, b1 = {0,0,0,0};
        if (n0 + srow < N) {
            const float* p = Bmat + (size_t)(n0 + srow) * ldb + k0 + scol;
            b0 = *(const float4*)p; b1 = *(const float4*)(p + 4);
        }
        __syncthreads();   // previous tile's reads complete before overwrite
        As[scol + 0][srow] = a0.x; As[scol + 1][srow] = a0.y;
        As[scol + 2][srow] = a0.z; As[scol + 3][srow] = a0.w;
        As[scol + 4][srow] = a1.x; As[scol + 5][srow] = a1.y;
        As[scol + 6][srow] = a1.z; As[scol + 7][srow] = a1.w;
        Bs[scol + 0][srow] = b0.x; Bs[scol + 1][srow] = b0.y;
        Bs[scol + 2][srow] = b0.z; Bs[scol + 3][srow] = b0.w;
        Bs[scol + 4][srow] = b1.x; Bs[scol + 5][srow] = b1.y;
        Bs[scol + 6][srow] = b1.z; Bs[scol + 7][srow] = b1.w;
        __syncthreads();
        #pragma unroll
        for (int kk = 0; kk < 16; ++kk) {
            const float4 aL = *(const float4*)&As[kk][ty * 4];
            const float4 aH = *(const float4*)&As[kk][64 + ty * 4];
            const float4 bL = *(const float4*)&Bs[kk][tx * 4];
            const float4 bH = *(const float4*)&Bs[kk][64 + tx * 4];
            const float aa[8] = {aL.x, aL.y, aL.z, aL.w, aH.x, aH.y, aH.z, aH.w};
            const float bb[8] = {bL.x, bL.y, bL.z, bL.w, bH.x, bH.y, bH.z, bH.w};
            #pragma unroll
            for (int r = 0; r < 8; ++r)
                #pragma unroll
                for (int c = 0; c < 8; ++c) acc[r][c] += aa[r] * bb[c];
        }
    }

    #pragma unroll
    for (int r = 0; r < 8; ++r) {
        const int m = m0 + ((r < 4) ? (ty * 4 + r) : (64 + ty * 4 + r - 4));
        if (m >= M) continue;
        const float bm = (bm1 ? bm1[m] : 0.f) + (bm2 ? bm2[m] : 0.f);
        #pragma unroll
        for (int h = 0; h < 2; ++h) {
            const int n = n0 + h * 64 + tx * 4;
            if (n + 3 < N) {
                float4 o;
                o.x = acc[r][h * 4 + 0] + bm + (bnv ? bnv[n + 0] : 0.f);
                o.y = acc[r][h * 4 + 1] + bm + (bnv ? bnv[n + 1] : 0.f);
                o.z = acc[r][h * 4 + 2] + bm + (bnv ? bnv[n + 2] : 0.f);
                o.w = acc[r][h * 4 + 3] + bm + (bnv ? bnv[n + 3] : 0.f);
                *(float4*)&C[(size_t)m * ldc + n] = o;
            } else {
                #pragma unroll
                for (int c = 0; c < 4; ++c)
                    if (n + c < N)
                        C[(size_t)m * ldc + n + c] =
                            acc[r][h * 4 + c] + bm + (bnv ? bnv[n + c] : 0.f);
            }
        }
    }
}

// ---------------- persistent bidirectional LSTM ----------------
// 256 blocks = {dir(2)} x {u-quad(64)} x {b-half(2)}. Block = 64 b x 4 u.
// Wave = 64 lanes = one u (wave-uniform weight rows -> scalar loads).
// c-state in register; h double-buffered in global: hT[dir][buf][k][b].
__global__ __launch_bounds__(256) void lstm_kernel(
    const float* __restrict__ Gf, const float* __restrict__ Gb,
    const float* __restrict__ Whh_f, const float* __restrict__ Whh_b,
    float* __restrict__ hT, float* __restrict__ lstm_out, int* cnt)
{
    const int blk = blockIdx.x;
    const int dir = blk >> 7;
    const int r   = blk & 127;
    const int u0  = (r >> 1) * 4;
    const int b0  = (r & 1) * 64;
    const int tid = threadIdx.x;
    const int b   = b0 + (tid & 63);
    const int uh  = __builtin_amdgcn_readfirstlane(tid >> 6);  // wave-uniform
    const int u   = u0 + uh;
    const float* __restrict__ G   = dir ? Gb : Gf;
    const float* __restrict__ Whh = dir ? Whh_b : Whh_f;
    float* __restrict__ hb = hT + (size_t)dir * (2 * HL * NB);
    const float* __restrict__ w0 = Whh + (size_t)(0 * HL + u) * HL;  // i
    const float* __restrict__ w1 = Whh + (size_t)(1 * HL + u) * HL;  // f
    const float* __restrict__ w2 = Whh + (size_t)(2 * HL + u) * HL;  // g
    const float* __restrict__ w3 = Whh + (size_t)(3 * HL + u) * HL;  // o
    const float* __restrict__ g0 = G + (size_t)(0 * HL + u) * 3200;
    const float* __restrict__ g1 = G + (size_t)(1 * HL + u) * 3200;
    const float* __restrict__ g2 = G + (size_t)(2 * HL + u) * 3200;
    const float* __restrict__ g3 = G + (size_t)(3 * HL + u) * 3200;
    int* mycnt = cnt + dir;

    float c = 0.f;
    for (int s = 0; s < NT; ++s) {
        const int t = dir ? (NT - 1 - s) : s;
        const int wb = s & 1, rb = wb ^ 1;
        float a0 = 0.f, a1 = 0.f, a2 = 0.f, a3 = 0.f;
        if (s) {
            const float* __restrict__ hr = hb + (size_t)rb * (HL * NB);
            #pragma unroll 8
            for (int k = 0; k < HL; ++k) {
                const float hv = hr[k * NB + b];
                a0 += w0[k] * hv; a1 += w1[k] * hv;
                a2 += w2[k] * hv; a3 += w3[k] * hv;
            }
        }
        const int col = t * NB + b;
        const float gi = sigm(a0 + g0[col]);
        const float gf = sigm(a1 + g1[col]);
        const float gg = tanhf(a2 + g2[col]);
        const float go = sigm(a3 + g3[col]);
        c = gf * c + gi * gg;
        const float h = go * tanhf(c);
        hb[(size_t)wb * (HL * NB) + u * NB + b] = h;
        lstm_out[((size_t)t * NB + b) * NCH + dir * HL + u] = h;
        if (s < NT - 1) gridbar(mycnt, 128 * (s + 1));
    }
}

// ---------------- persistent GRU decoder ----------------
// 256 blocks = {u-quad(128)} x {b-half(2)}. Block = 64 b x 4 u; h double-buffered.
__global__ __launch_bounds__(256) void gru_kernel(
    const float* __restrict__ Gx, const float* __restrict__ embtab,
    const int* __restrict__ text, const float* __restrict__ Whh,
    const float* __restrict__ bhh, float* __restrict__ hgT,
    float* __restrict__ gru_out, int* cnt)
{
    const int blk = blockIdx.x;
    const int u0  = (blk >> 1) * 4;
    const int b0  = (blk & 1) * 64;
    const int tid = threadIdx.x;
    const int b   = b0 + (tid & 63);
    const int uh  = __builtin_amdgcn_readfirstlane(tid >> 6);
    const int u   = u0 + uh;
    const float* __restrict__ wr = Whh + (size_t)(0 * 512 + u) * 512;
    const float* __restrict__ wz = Whh + (size_t)(1 * 512 + u) * 512;
    const float* __restrict__ wn = Whh + (size_t)(2 * 512 + u) * 512;
    const float* __restrict__ gr = Gx + (size_t)(0 * 512 + u) * 3200;
    const float* __restrict__ gz = Gx + (size_t)(1 * 512 + u) * 3200;
    const float* __restrict__ gn = Gx + (size_t)(2 * 512 + u) * 3200;
    const float br = bhh[u], bz = bhh[512 + u], bn_ = bhh[1024 + u];

    float h = 0.f;
    for (int t = 0; t < NT; ++t) {
        const int wb = t & 1, rb = wb ^ 1;
        float ar = 0.f, az = 0.f, an = 0.f;
        if (t) {
            const float* __restrict__ hr = hgT + (size_t)rb * (512 * NB);
            #pragma unroll 8
            for (int k = 0; k < 512; ++k) {
                const float hv = hr[k * NB + b];
                ar += wr[k] * hv; az += wz[k] * hv; an += wn[k] * hv;
            }
        }
        const int tok = t ? text[b * NT + t - 1] : 0;
        const float* __restrict__ et = embtab + (size_t)tok * 1536;
        const int col = t * NB + b;
        const float rg = sigm(gr[col] + et[u]         + ar + br);
        const float z  = sigm(gz[col] + et[512 + u]   + az + bz);
        const float n  = tanhf(gn[col] + et[1024 + u] + rg * (an + bn_));
        h = (1.f - z) * n + z * h;
        hgT[(size_t)wb * (512 * NB) + u * NB + b] = h;
        gru_out[((size_t)t * NB + b) * NCH + u] = h;
        if (t < NT - 1) gridbar(cnt, 256 * (t + 1));
    }
}

// ---------------- generator + ragged gather ----------------
__global__ __launch_bounds__(64) void gen_gather_kernel(
    const float* __restrict__ gru_out, const float* __restrict__ Wg,
    const float* __restrict__ bg, const float* __restrict__ An,
    const int* __restrict__ pfx, const int* __restrict__ tlen,
    float* __restrict__ out)
{
    const int b = blockIdx.x / NT;
    const int t = blockIdx.x % NT;
    if (t >= tlen[b]) return;
    const int row = pfx[b] + t;
    const int L = pfx[NB];
    const int lane = threadIdx.x;

    __shared__ float xs[512];
    const float* x = gru_out + ((size_t)t * NB + b) * NCH;
    for (int i = lane; i < 512; i += 64) xs[i] = x[i];
    __syncthreads();

    if (lane < NCLS) {
        const float4* wrow = (const float4*)(Wg + (size_t)lane * 512);
        float acc = bg[lane];
        #pragma unroll 4
        for (int k4 = 0; k4 < 128; ++k4) {
            const float4 w = wrow[k4];
            const float4 xv = *(const float4*)&xs[k4 * 4];
            acc += w.x * xv.x + w.y * xv.y + w.z * xv.z + w.w * xv.w;
        }
        out[(size_t)row * NCLS + lane] = acc;
    }
    const float* an = An + ((size_t)b * NT + t) * NHW;
    float* oa = out + (size_t)L * NCLS + (size_t)row * NHW;
    for (int i = lane; i < NHW; i += 64) oa[i] = an[i];
}

// ---------------- launch ----------------
extern "C" void kernel_launch(void* const* d_in, const int* in_sizes, int n_in,
                              void* d_out, int out_size, void* d_ws, size_t ws_size,
                              hipStream_t stream)
{
    const float* feature = (const float*)d_in[0];
    const float* A       = (const float*)d_in[1];
    const int*   text    = (const int*)d_in[2];
    const int*   tlen    = (const int*)d_in[3];
    const float* W_ih_f  = (const float*)d_in[4];
    const float* W_hh_f  = (const float*)d_in[5];
    const float* b_ih_f  = (const float*)d_in[6];
    const float* b_hh_f  = (const float*)d_in[7];
    const float* W_ih_b  = (const float*)d_in[8];
    const float* W_hh_b  = (const float*)d_in[9];
    const float* b_ih_b  = (const float*)d_in[10];
    const float* b_hh_b  = (const float*)d_in[11];
    const float* W_ih_g  = (const float*)d_in[12];
    const float* W_hh_g  = (const float*)d_in[13];
    const float* b_ih_g  = (const float*)d_in[14];
    const float* b_hh_g  = (const float*)d_in[15];
    const float* W_gen   = (const float*)d_in[16];
    const float* b_gen   = (const float*)d_in[17];
    const float* cemb    = (const float*)d_in[18];

    float* ws       = (float*)d_ws;
    float* Anorm    = ws + OFF_ANORM;
    float* Cpool    = ws + OFF_CPOOL;
    float* hT       = ws + OFF_HT;      // aliases Cpool (dead by then)
    float* hgT      = ws + OFF_HGT;     // aliases Cpool
    float* Gf       = ws + OFF_GF;
    float* Gb       = ws + OFF_GB;
    float* Gx       = ws + OFF_GX;      // aliases Gf/Gb (dead by then)
    float* lstm_out = ws + OFF_LSTMOUT;
    float* gru_out  = ws + OFF_GRUOUT;  // aliases lstm_out (dead by then)
    float* embtab   = ws + OFF_EMBTAB;
    int*   ip       = (int*)(ws + OFF_INT);
    int*   cnt      = ip;               // [0]=lstm fwd, [1]=lstm bwd, [2]=gru
    int*   pfx      = ip + 8;

    // zero the barrier counters (ws is poisoned 0xAA before every call)
    hipMemsetAsync(cnt, 0, 16, stream);

    prefix_kernel<<<1, 64, 0, stream>>>(tlen, pfx);
    norm_attn_kernel<<<NB * NT, 256, 0, stream>>>(A, Anorm);
    pool_kernel<<<dim3(2, NB), 256, 0, stream>>>(feature, Anorm, Cpool);

    // LSTM input gates, transposed: G'[row(1024)][t*128+b], bias = b_ih + b_hh
    gemm_tn_kernel<<<dim3(25, 8), 256, 0, stream>>>(1024, 3200, 512,
        W_ih_f, 512, Cpool, 512, b_ih_f, b_hh_f, nullptr, Gf, 3200);
    gemm_tn_kernel<<<dim3(25, 8), 256, 0, stream>>>(1024, 3200, 512,
        W_ih_b, 512, Cpool, 512, b_ih_b, b_hh_b, nullptr, Gb, 3200);
    // emb table: embtab[tok][row] = cemb @ W_ih_g[:,512:]^T + b_ih_g
    gemm_tn_kernel<<<dim3(12, 1), 256, 0, stream>>>(38, 1536, 512,
        cemb, 512, W_ih_g + 512, 1024, nullptr, nullptr, b_ih_g, embtab, 1536);

    lstm_kernel<<<256, 256, 0, stream>>>(Gf, Gb, W_hh_f, W_hh_b, hT, lstm_out, cnt);

    // GRU input gates from LSTM outputs (no bias; emb part carries b_ih_g)
    gemm_tn_kernel<<<dim3(25, 12), 256, 0, stream>>>(1536, 3200, 512,
        W_ih_g, 1024, lstm_out, 512, nullptr, nullptr, nullptr, Gx, 3200);

    gru_kernel<<<256, 256, 0, stream>>>(Gx, embtab, text, W_hh_g, b_hh_g, hgT, gru_out, cnt + 2);

    gen_gather_kernel<<<NB * NT, 64, 0, stream>>>(gru_out, W_gen, b_gen, Anorm, pfx, tlen, (float*)d_out);
}

// Round 4
// 2335.849 us; speedup vs baseline: 1.0021x; 1.0021x over previous
//
#include <hip/hip_runtime.h>
#include <math.h>

// Problem constants
#define NB   128
#define NT   25
#define NCH  512
#define HL   256      // LSTM hidden per direction
#define NHW  256      // 8*32
#define NCLS 38

// ---------------- workspace layout (float offsets) ----------------
// Anorm lives whole run. Cpool dead after LSTM-input GEMMs -> hT/hgT alias it.
// lstm_out dead after GRU-x GEMM -> gru_out aliases it.
#define OFF_ANORM   0u
#define SZ_ANORM    (128u*25u*256u)              // 819200
#define OFF_CPOOL   (OFF_ANORM + SZ_ANORM)       // 819200
#define SZ_CPOOL    (25u*128u*512u)              // 1638400
#define OFF_HT      OFF_CPOOL                    // alias: 2dir*2buf*128b*256k = 131072
#define OFF_HGT     (OFF_CPOOL + 131072u)        // alias: 2buf*128b*512k      = 131072
#define OFF_G       (OFF_CPOOL + SZ_CPOOL)       // 2457600
#define SZ_GF       (1024u*3200u)                // 3276800
#define OFF_GF      OFF_G
#define OFF_GB      (OFF_G + SZ_GF)
#define OFF_GX      OFF_G                        // alias: 1536*3200 <= 2*SZ_GF
#define OFF_LSTMOUT (OFF_G + 2u*SZ_GF)           // 9011200
#define SZ_LSTMOUT  (25u*128u*512u)              // 1638400
#define OFF_GRUOUT  OFF_LSTMOUT                  // alias: lstm_out dead when gru writes
#define OFF_EMBTAB  (OFF_LSTMOUT + SZ_LSTMOUT)   // 10649600
#define SZ_EMBTAB   (38u*1536u)                  // 58368
#define OFF_INT     (OFF_EMBTAB + SZ_EMBTAB)     // 10707968: [0..3]=cnt, [8..]=pfx

__device__ __forceinline__ float sigm(float x) { return 1.0f / (1.0f + expf(-x)); }

// ---------------- grid barrier (agent scope, cross-XCD safe) ----------------
// Store-side: __syncthreads drains each wave's stores to L2 (compiler emits
// s_waitcnt vmcnt(0) before s_barrier); leader's RELEASE add emits L2
// writeback before bumping the counter at the coherence point.
// Load-side: ALL threads run the agent acquire fence (L1/L2 invalidate)
// after the leader observes the target.
__device__ __forceinline__ void gridbar(int* cnt, int target) {
    __syncthreads();
    if (threadIdx.x == 0) {
        __hip_atomic_fetch_add(cnt, 1, __ATOMIC_RELEASE, __HIP_MEMORY_SCOPE_AGENT);
        while (__hip_atomic_load(cnt, __ATOMIC_RELAXED, __HIP_MEMORY_SCOPE_AGENT) < target) {
            __builtin_amdgcn_s_sleep(2);
        }
    }
    __syncthreads();
    __builtin_amdgcn_fence(__ATOMIC_ACQUIRE, "agent");
}

// ---------------- prefix sums of text_length ----------------
__global__ void prefix_kernel(const int* __restrict__ tlen, int* __restrict__ pfx) {
    if (threadIdx.x == 0) {
        int s = 0;
        for (int i = 0; i < NB; ++i) { pfx[i] = s; s += tlen[i]; }
        pfx[NB] = s;
    }
}

// ---------------- normalize attention maps per (b,t) ----------------
__global__ __launch_bounds__(256) void norm_attn_kernel(const float* __restrict__ A,
                                                        float* __restrict__ An) {
    const int bt = blockIdx.x;             // b*25 + t
    const int tid = threadIdx.x;
    float v = A[(size_t)bt * NHW + tid];
    float s = v;
    #pragma unroll
    for (int off = 32; off > 0; off >>= 1) s += __shfl_down(s, off, 64);
    __shared__ float wsum[4];
    if ((tid & 63) == 0) wsum[tid >> 6] = s;
    __syncthreads();
    float tot = wsum[0] + wsum[1] + wsum[2] + wsum[3];
    An[(size_t)bt * NHW + tid] = v / tot;
}

// ---------------- attention-weighted pooling: Cpool[t][b][c] = sum_hw feat[b][c][hw]*An[b][t][hw]
__global__ __launch_bounds__(256) void pool_kernel(const float* __restrict__ feature,
                                                   const float* __restrict__ An,
                                                   float* __restrict__ Cpool) {
    __shared__ float al[25][256];          // 25.6 KB
    const int b = blockIdx.y;
    const int c = blockIdx.x * 256 + threadIdx.x;
    for (int i = threadIdx.x; i < 25 * 256; i += 256)
        al[i >> 8][i & 255] = An[(size_t)b * 25 * 256 + i];
    __syncthreads();
    const float* f = feature + ((size_t)b * NCH + c) * NHW;
    float acc[25];
    #pragma unroll
    for (int t = 0; t < 25; ++t) acc[t] = 0.f;
    for (int hw = 0; hw < NHW; hw += 4) {
        const float4 fv = *(const float4*)(f + hw);
        #pragma unroll
        for (int t = 0; t < 25; ++t) {
            const float4 av = *(const float4*)&al[t][hw];
            acc[t] += fv.x * av.x + fv.y * av.y + fv.z * av.z + fv.w * av.w;
        }
    }
    #pragma unroll
    for (int t = 0; t < 25; ++t)
        Cpool[((size_t)t * NB + b) * NCH + c] = acc[t];
}

// ---------------- fp32 GEMM: C[m][n] = sum_k A[m][k]*B[n][k] (+bm1[m]+bm2[m]+bn[n])
// 128x128 tile, BK=16, 256 threads, 8x8 acc/thread in 4 quadrants.
__global__ __launch_bounds__(256) void gemm_tn_kernel(
    int M, int N, int K,
    const float* __restrict__ Amat, int lda,
    const float* __restrict__ Bmat, int ldb,
    const float* __restrict__ bm1, const float* __restrict__ bm2,
    const float* __restrict__ bnv,
    float* __restrict__ C, int ldc)
{
    __shared__ float As[16][128];
    __shared__ float Bs[16][128];
    const int tid = threadIdx.x;
    const int m0 = blockIdx.y * 128;
    const int n0 = blockIdx.x * 128;
    const int ty = tid >> 4, tx = tid & 15;
    const int srow = tid >> 1, scol = (tid & 1) * 8;   // staging: row, k-offset

    float acc[8][8];
    #pragma unroll
    for (int r = 0; r < 8; ++r)
        #pragma unroll
        for (int c = 0; c < 8; ++c) acc[r][c] = 0.f;

    for (int k0 = 0; k0 < K; k0 += 16) {
        float4 a0 = {0,0,0,0}, a1 = {0,0,0,0};
        if (m0 + srow < M) {
            const float* p = Amat + (size_t)(m0 + srow) * lda + k0 + scol;
            a0 = *(const float4*)p; a1 = *(const float4*)(p + 4);
        }
        float4 b0 = {0,0,0,0}, b1 = {0,0,0,0};
        if (n0 + srow < N) {
            const float* p = Bmat + (size_t)(n0 + srow) * ldb + k0 + scol;
            b0 = *(const float4*)p; b1 = *(const float4*)(p + 4);
        }
        __syncthreads();   // previous tile's reads complete before overwrite
        As[scol + 0][srow] = a0.x; As[scol + 1][srow] = a0.y;
        As[scol + 2][srow] = a0.z; As[scol + 3][srow] = a0.w;
        As[scol + 4][srow] = a1.x; As[scol + 5][srow] = a1.y;
        As[scol + 6][srow] = a1.z; As[scol + 7][srow] = a1.w;
        Bs[scol + 0][srow] = b0.x; Bs[scol + 1][srow] = b0.y;
        Bs[scol + 2][srow] = b0.z; Bs[scol + 3][srow] = b0.w;
        Bs[scol + 4][srow] = b1.x; Bs[scol + 5][srow] = b1.y;
        Bs[scol + 6][srow] = b1.z; Bs[scol + 7][srow] = b1.w;
        __syncthreads();
        #pragma unroll
        for (int kk = 0; kk < 16; ++kk) {
            const float4 aL = *(const float4*)&As[kk][ty * 4];
            const float4 aH = *(const float4*)&As[kk][64 + ty * 4];
            const float4 bL = *(const float4*)&Bs[kk][tx * 4];
            const float4 bH = *(const float4*)&Bs[kk][64 + tx * 4];
            const float aa[8] = {aL.x, aL.y, aL.z, aL.w, aH.x, aH.y, aH.z, aH.w};
            const float bb[8] = {bL.x, bL.y, bL.z, bL.w, bH.x, bH.y, bH.z, bH.w};
            #pragma unroll
            for (int r = 0; r < 8; ++r)
                #pragma unroll
                for (int c = 0; c < 8; ++c) acc[r][c] += aa[r] * bb[c];
        }
    }

    #pragma unroll
    for (int r = 0; r < 8; ++r) {
        const int m = m0 + ((r < 4) ? (ty * 4 + r) : (64 + ty * 4 + r - 4));
        if (m >= M) continue;
        const float bm = (bm1 ? bm1[m] : 0.f) + (bm2 ? bm2[m] : 0.f);
        #pragma unroll
        for (int h = 0; h < 2; ++h) {
            const int n = n0 + h * 64 + tx * 4;
            if (n + 3 < N) {
                float4 o;
                o.x = acc[r][h * 4 + 0] + bm + (bnv ? bnv[n + 0] : 0.f);
                o.y = acc[r][h * 4 + 1] + bm + (bnv ? bnv[n + 1] : 0.f);
                o.z = acc[r][h * 4 + 2] + bm + (bnv ? bnv[n + 2] : 0.f);
                o.w = acc[r][h * 4 + 3] + bm + (bnv ? bnv[n + 3] : 0.f);
                *(float4*)&C[(size_t)m * ldc + n] = o;
            } else {
                #pragma unroll
                for (int c = 0; c < 4; ++c)
                    if (n + c < N)
                        C[(size_t)m * ldc + n + c] =
                            acc[r][h * 4 + c] + bm + (bnv ? bnv[n + c] : 0.f);
            }
        }
    }
}

// ---------------- persistent bidirectional LSTM ----------------
// 256 blocks = {dir(2)} x {u-quad(64)} x {b-half(2)}. Block = 64 b x 4 u.
// Wave = 64 lanes = one u (wave-uniform weight rows -> scalar loads).
// c-state in register; h double-buffered in global, ROW-PER-BATCH layout:
// hT[dir][buf][b][k] -> per-thread contiguous float4 row reads (128 loads
// replaced the 512 strided scalar loads that made round-3 latency-bound).
__global__ __launch_bounds__(256) void lstm_kernel(
    const float* __restrict__ Gf, const float* __restrict__ Gb,
    const float* __restrict__ Whh_f, const float* __restrict__ Whh_b,
    float* __restrict__ hT, float* __restrict__ lstm_out, int* cnt)
{
    const int blk = blockIdx.x;
    const int dir = blk >> 7;
    const int r   = blk & 127;
    const int u0  = (r >> 1) * 4;
    const int b0  = (r & 1) * 64;
    const int tid = threadIdx.x;
    const int b   = b0 + (tid & 63);
    const int uh  = __builtin_amdgcn_readfirstlane(tid >> 6);  // wave-uniform
    const int u   = u0 + uh;
    const float* __restrict__ G   = dir ? Gb : Gf;
    const float* __restrict__ Whh = dir ? Whh_b : Whh_f;
    float* __restrict__ hb = hT + (size_t)dir * (2 * NB * HL);
    const float* __restrict__ w0 = Whh + (size_t)(0 * HL + u) * HL;  // i
    const float* __restrict__ w1 = Whh + (size_t)(1 * HL + u) * HL;  // f
    const float* __restrict__ w2 = Whh + (size_t)(2 * HL + u) * HL;  // g
    const float* __restrict__ w3 = Whh + (size_t)(3 * HL + u) * HL;  // o
    const float* __restrict__ g0 = G + (size_t)(0 * HL + u) * 3200;
    const float* __restrict__ g1 = G + (size_t)(1 * HL + u) * 3200;
    const float* __restrict__ g2 = G + (size_t)(2 * HL + u) * 3200;
    const float* __restrict__ g3 = G + (size_t)(3 * HL + u) * 3200;
    int* mycnt = cnt + dir;

    // step-0 gate prefetch (registers survive the fence; caches don't)
    int col = (dir ? (NT - 1) : 0) * NB + b;
    float p0 = g0[col], p1 = g1[col], p2 = g2[col], p3 = g3[col];

    float c = 0.f;
    for (int s = 0; s < NT; ++s) {
        const int wb = s & 1, rb = wb ^ 1;
        float a0 = 0.f, a1 = 0.f, a2 = 0.f, a3 = 0.f;
        if (s) {
            const float* __restrict__ hrow = hb + (size_t)rb * (NB * HL) + (size_t)b * HL;
            #pragma unroll 8
            for (int k4 = 0; k4 < HL / 4; ++k4) {
                const float4 hv = ((const float4*)hrow)[k4];
                const int k = k4 * 4;
                a0 += w0[k]*hv.x + w0[k+1]*hv.y + w0[k+2]*hv.z + w0[k+3]*hv.w;
                a1 += w1[k]*hv.x + w1[k+1]*hv.y + w1[k+2]*hv.z + w1[k+3]*hv.w;
                a2 += w2[k]*hv.x + w2[k+1]*hv.y + w2[k+2]*hv.z + w2[k+3]*hv.w;
                a3 += w3[k]*hv.x + w3[k+1]*hv.y + w3[k+2]*hv.z + w3[k+3]*hv.w;
            }
        }
        const float gi = sigm(a0 + p0);
        const float gf = sigm(a1 + p1);
        const float gg = tanhf(a2 + p2);
        const float go = sigm(a3 + p3);
        c = gf * c + gi * gg;
        const float h = go * tanhf(c);
        const int t = dir ? (NT - 1 - s) : s;
        hb[(size_t)wb * (NB * HL) + (size_t)b * HL + u] = h;
        lstm_out[((size_t)t * NB + b) * NCH + dir * HL + u] = h;
        if (s < NT - 1) {
            const int tn = dir ? (NT - 2 - s) : (s + 1);
            col = tn * NB + b;
            p0 = g0[col]; p1 = g1[col]; p2 = g2[col]; p3 = g3[col];
            gridbar(mycnt, 128 * (s + 1));
        }
    }
}

// ---------------- persistent GRU decoder ----------------
// 256 blocks = {u-quad(128)} x {b-half(2)}. Block = 64 b x 4 u.
// h double-buffered, row-per-batch: hgT[buf][b][k].
__global__ __launch_bounds__(256) void gru_kernel(
    const float* __restrict__ Gx, const float* __restrict__ embtab,
    const int* __restrict__ text, const float* __restrict__ Whh,
    const float* __restrict__ bhh, float* __restrict__ hgT,
    float* __restrict__ gru_out, int* cnt)
{
    const int blk = blockIdx.x;
    const int u0  = (blk >> 1) * 4;
    const int b0  = (blk & 1) * 64;
    const int tid = threadIdx.x;
    const int b   = b0 + (tid & 63);
    const int uh  = __builtin_amdgcn_readfirstlane(tid >> 6);
    const int u   = u0 + uh;
    const float* __restrict__ wr = Whh + (size_t)(0 * 512 + u) * 512;
    const float* __restrict__ wz = Whh + (size_t)(1 * 512 + u) * 512;
    const float* __restrict__ wn = Whh + (size_t)(2 * 512 + u) * 512;
    const float* __restrict__ gr = Gx + (size_t)(0 * 512 + u) * 3200;
    const float* __restrict__ gz = Gx + (size_t)(1 * 512 + u) * 3200;
    const float* __restrict__ gn = Gx + (size_t)(2 * 512 + u) * 3200;
    const float br = bhh[u], bz = bhh[512 + u], bn_ = bhh[1024 + u];

    // step-0 prefetch: gates + embedding for tok=0
    float pr = gr[b], pz = gz[b], pn = gn[b];
    float er = embtab[u], ez = embtab[512 + u], en = embtab[1024 + u];

    float h = 0.f;
    for (int t = 0; t < NT; ++t) {
        const int wb = t & 1, rb = wb ^ 1;
        float ar = 0.f, az = 0.f, an = 0.f;
        if (t) {
            const float* __restrict__ hrow = hgT + (size_t)rb * (NB * 512) + (size_t)b * 512;
            #pragma unroll 8
            for (int k4 = 0; k4 < 128; ++k4) {
                const float4 hv = ((const float4*)hrow)[k4];
                const int k = k4 * 4;
                ar += wr[k]*hv.x + wr[k+1]*hv.y + wr[k+2]*hv.z + wr[k+3]*hv.w;
                az += wz[k]*hv.x + wz[k+1]*hv.y + wz[k+2]*hv.z + wz[k+3]*hv.w;
                an += wn[k]*hv.x + wn[k+1]*hv.y + wn[k+2]*hv.z + wn[k+3]*hv.w;
            }
        }
        const float rg = sigm(pr + er + ar + br);
        const float z  = sigm(pz + ez + az + bz);
        const float n  = tanhf(pn + en + rg * (an + bn_));
        h = (1.f - z) * n + z * h;
        hgT[(size_t)wb * (NB * 512) + (size_t)b * 512 + u] = h;
        gru_out[((size_t)t * NB + b) * NCH + u] = h;
        if (t < NT - 1) {
            const int col = (t + 1) * NB + b;
            pr = gr[col]; pz = gz[col]; pn = gn[col];
            const int tok = text[b * NT + t];
            const float* __restrict__ et = embtab + (size_t)tok * 1536;
            er = et[u]; ez = et[512 + u]; en = et[1024 + u];
            gridbar(cnt, 256 * (t + 1));
        }
    }
}

// ---------------- generator + ragged gather ----------------
__global__ __launch_bounds__(64) void gen_gather_kernel(
    const float* __restrict__ gru_out, const float* __restrict__ Wg,
    const float* __restrict__ bg, const float* __restrict__ An,
    const int* __restrict__ pfx, const int* __restrict__ tlen,
    float* __restrict__ out)
{
    const int b = blockIdx.x / NT;
    const int t = blockIdx.x % NT;
    if (t >= tlen[b]) return;
    const int row = pfx[b] + t;
    const int L = pfx[NB];
    const int lane = threadIdx.x;

    __shared__ float xs[512];
    const float* x = gru_out + ((size_t)t * NB + b) * NCH;
    for (int i = lane; i < 512; i += 64) xs[i] = x[i];
    __syncthreads();

    if (lane < NCLS) {
        const float4* wrow = (const float4*)(Wg + (size_t)lane * 512);
        float acc = bg[lane];
        #pragma unroll 4
        for (int k4 = 0; k4 < 128; ++k4) {
            const float4 w = wrow[k4];
            const float4 xv = *(const float4*)&xs[k4 * 4];
            acc += w.x * xv.x + w.y * xv.y + w.z * xv.z + w.w * xv.w;
        }
        out[(size_t)row * NCLS + lane] = acc;
    }
    const float* an = An + ((size_t)b * NT + t) * NHW;
    float* oa = out + (size_t)L * NCLS + (size_t)row * NHW;
    for (int i = lane; i < NHW; i += 64) oa[i] = an[i];
}

// ---------------- launch ----------------
extern "C" void kernel_launch(void* const* d_in, const int* in_sizes, int n_in,
                              void* d_out, int out_size, void* d_ws, size_t ws_size,
                              hipStream_t stream)
{
    const float* feature = (const float*)d_in[0];
    const float* A       = (const float*)d_in[1];
    const int*   text    = (const int*)d_in[2];
    const int*   tlen    = (const int*)d_in[3];
    const float* W_ih_f  = (const float*)d_in[4];
    const float* W_hh_f  = (const float*)d_in[5];
    const float* b_ih_f  = (const float*)d_in[6];
    const float* b_hh_f  = (const float*)d_in[7];
    const float* W_ih_b  = (const float*)d_in[8];
    const float* W_hh_b  = (const float*)d_in[9];
    const float* b_ih_b  = (const float*)d_in[10];
    const float* b_hh_b  = (const float*)d_in[11];
    const float* W_ih_g  = (const float*)d_in[12];
    const float* W_hh_g  = (const float*)d_in[13];
    const float* b_ih_g  = (const float*)d_in[14];
    const float* b_hh_g  = (const float*)d_in[15];
    const float* W_gen   = (const float*)d_in[16];
    const float* b_gen   = (const float*)d_in[17];
    const float* cemb    = (const float*)d_in[18];

    float* ws       = (float*)d_ws;
    float* Anorm    = ws + OFF_ANORM;
    float* Cpool    = ws + OFF_CPOOL;
    float* hT       = ws + OFF_HT;      // aliases Cpool (dead by then)
    float* hgT      = ws + OFF_HGT;     // aliases Cpool
    float* Gf       = ws + OFF_GF;
    float* Gb       = ws + OFF_GB;
    float* Gx       = ws + OFF_GX;      // aliases Gf/Gb (dead by then)
    float* lstm_out = ws + OFF_LSTMOUT;
    float* gru_out  = ws + OFF_GRUOUT;  // aliases lstm_out (dead by then)
    float* embtab   = ws + OFF_EMBTAB;
    int*   ip       = (int*)(ws + OFF_INT);
    int*   cnt      = ip;               // [0]=lstm fwd, [1]=lstm bwd, [2]=gru
    int*   pfx      = ip + 8;

    // zero the barrier counters (ws is poisoned 0xAA before every call)
    hipMemsetAsync(cnt, 0, 16, stream);

    prefix_kernel<<<1, 64, 0, stream>>>(tlen, pfx);
    norm_attn_kernel<<<NB * NT, 256, 0, stream>>>(A, Anorm);
    pool_kernel<<<dim3(2, NB), 256, 0, stream>>>(feature, Anorm, Cpool);

    // LSTM input gates, transposed: G'[row(1024)][t*128+b], bias = b_ih + b_hh
    gemm_tn_kernel<<<dim3(25, 8), 256, 0, stream>>>(1024, 3200, 512,
        W_ih_f, 512, Cpool, 512, b_ih_f, b_hh_f, nullptr, Gf, 3200);
    gemm_tn_kernel<<<dim3(25, 8), 256, 0, stream>>>(1024, 3200, 512,
        W_ih_b, 512, Cpool, 512, b_ih_b, b_hh_b, nullptr, Gb, 3200);
    // emb table: embtab[tok][row] = cemb @ W_ih_g[:,512:]^T + b_ih_g
    gemm_tn_kernel<<<dim3(12, 1), 256, 0, stream>>>(38, 1536, 512,
        cemb, 512, W_ih_g + 512, 1024, nullptr, nullptr, b_ih_g, embtab, 1536);

    lstm_kernel<<<256, 256, 0, stream>>>(Gf, Gb, W_hh_f, W_hh_b, hT, lstm_out, cnt);

    // GRU input gates from LSTM outputs (no bias; emb part carries b_ih_g)
    gemm_tn_kernel<<<dim3(25, 12), 256, 0, stream>>>(1536, 3200, 512,
        W_ih_g, 1024, lstm_out, 512, nullptr, nullptr, nullptr, Gx, 3200);

    gru_kernel<<<256, 256, 0, stream>>>(Gx, embtab, text, W_hh_g, b_hh_g, hgT, gru_out, cnt + 2);

    gen_gather_kernel<<<NB * NT, 64, 0, stream>>>(gru_out, W_gen, b_gen, Anorm, pfx, tlen, (float*)d_out);
}

// Round 6
// 1788.858 us; speedup vs baseline: 1.3085x; 1.3058x over previous
//
#include <hip/hip_runtime.h>
#include <math.h>

// Problem constants
#define NB   128
#define NT   25
#define NCH  512
#define HL   256      // LSTM hidden per direction
#define NHW  256      // 8*32
#define NCLS 38

typedef float v4f __attribute__((ext_vector_type(4)));  // native vec for NT builtins

// ---------------- workspace layout (float offsets) ----------------
#define OFF_ANORM   0u
#define SZ_ANORM    (128u*25u*256u)              // 819200
#define OFF_CPOOL   (OFF_ANORM + SZ_ANORM)       // 819200
#define SZ_CPOOL    (25u*128u*512u)              // 1638400
#define OFF_HT      OFF_CPOOL                    // alias: 2dir*2buf*[256k][128b] = 131072
#define OFF_HGT     (OFF_CPOOL + 131072u)        // alias: 2buf*[512k][128b]      = 131072
#define OFF_G       (OFF_CPOOL + SZ_CPOOL)       // 2457600
#define SZ_GF       (1024u*3200u)                // 3276800
#define OFF_GF      OFF_G
#define OFF_GB      (OFF_G + SZ_GF)
#define OFF_GX      OFF_G                        // alias: 1536*3200 <= 2*SZ_GF
#define OFF_LSTMOUT (OFF_G + 2u*SZ_GF)           // 9011200: [512ch][3200]
#define SZ_LSTMOUT  (25u*128u*512u)              // 1638400
#define OFF_GRUOUT  OFF_LSTMOUT                  // alias: [25t][512u][128b]
#define OFF_EMBTAB  (OFF_LSTMOUT + SZ_LSTMOUT)   // 10649600
#define SZ_EMBTAB   (38u*1536u)                  // 58368
#define OFF_INT     (OFF_EMBTAB + SZ_EMBTAB)     // 10707968: [0..95]=cnt(64B-padded), [128..]=pfx

__device__ __forceinline__ float sigm(float x) { return 1.0f / (1.0f + expf(-x)); }

// ---------------- grid barrier ----------------
// All cross-block data moves via NONTEMPORAL stores/loads (bypass L1/L2, live at
// L3 = agent coherence point). __syncthreads drains vmcnt (NT stores complete)
// before the leader's release-add; release writeback is ~free (L2 has no dirty
// communicated lines). Consumers use NT loads -> NO acquire invalidate needed,
// so weights/gates stay L2-hot across all steps (round-4's 37us/step killer).
__device__ __forceinline__ void gridbar(int* cnt, int target) {
    __syncthreads();
    if (threadIdx.x == 0) {
        __hip_atomic_fetch_add(cnt, 1, __ATOMIC_RELEASE, __HIP_MEMORY_SCOPE_AGENT);
        while (__hip_atomic_load(cnt, __ATOMIC_RELAXED, __HIP_MEMORY_SCOPE_AGENT) < target) {
            __builtin_amdgcn_s_sleep(2);
        }
    }
    __syncthreads();
}

// ---------------- prefix sums of text_length ----------------
__global__ void prefix_kernel(const int* __restrict__ tlen, int* __restrict__ pfx) {
    if (threadIdx.x == 0) {
        int s = 0;
        for (int i = 0; i < NB; ++i) { pfx[i] = s; s += tlen[i]; }
        pfx[NB] = s;
    }
}

// ---------------- normalize attention maps per (b,t) ----------------
__global__ __launch_bounds__(256) void norm_attn_kernel(const float* __restrict__ A,
                                                        float* __restrict__ An) {
    const int bt = blockIdx.x;             // b*25 + t
    const int tid = threadIdx.x;
    float v = A[(size_t)bt * NHW + tid];
    float s = v;
    #pragma unroll
    for (int off = 32; off > 0; off >>= 1) s += __shfl_down(s, off, 64);
    __shared__ float wsum[4];
    if ((tid & 63) == 0) wsum[tid >> 6] = s;
    __syncthreads();
    float tot = wsum[0] + wsum[1] + wsum[2] + wsum[3];
    An[(size_t)bt * NHW + tid] = v / tot;
}

// ---------------- attention pooling: Cpool[t][b][c] = sum_hw feat[b][c][hw]*An[b][t][hw]
__global__ __launch_bounds__(256) void pool_kernel(const float* __restrict__ feature,
                                                   const float* __restrict__ An,
                                                   float* __restrict__ Cpool) {
    __shared__ float al[25][256];
    const int b = blockIdx.y;
    const int c = blockIdx.x * 256 + threadIdx.x;
    for (int i = threadIdx.x; i < 25 * 256; i += 256)
        al[i >> 8][i & 255] = An[(size_t)b * 25 * 256 + i];
    __syncthreads();
    const float* f = feature + ((size_t)b * NCH + c) * NHW;
    float acc[25];
    #pragma unroll
    for (int t = 0; t < 25; ++t) acc[t] = 0.f;
    for (int hw = 0; hw < NHW; hw += 4) {
        const float4 fv = *(const float4*)(f + hw);
        #pragma unroll
        for (int t = 0; t < 25; ++t) {
            const float4 av = *(const float4*)&al[t][hw];
            acc[t] += fv.x * av.x + fv.y * av.y + fv.z * av.z + fv.w * av.w;
        }
    }
    #pragma unroll
    for (int t = 0; t < 25; ++t)
        Cpool[((size_t)t * NB + b) * NCH + c] = acc[t];
}

// ---------------- fp32 GEMM (B row-major [n][k]): C[m][n] = sum_k A[m][k]*B[n][k]
__global__ __launch_bounds__(256) void gemm_tn_kernel(
    int M, int N, int K,
    const float* __restrict__ Amat, int lda,
    const float* __restrict__ Bmat, int ldb,
    const float* __restrict__ bm1, const float* __restrict__ bm2,
    const float* __restrict__ bnv,
    float* __restrict__ C, int ldc)
{
    __shared__ float As[16][128];
    __shared__ float Bs[16][128];
    const int tid = threadIdx.x;
    const int m0 = blockIdx.y * 128;
    const int n0 = blockIdx.x * 128;
    const int ty = tid >> 4, tx = tid & 15;
    const int srow = tid >> 1, scol = (tid & 1) * 8;

    float acc[8][8];
    #pragma unroll
    for (int r = 0; r < 8; ++r)
        #pragma unroll
        for (int c = 0; c < 8; ++c) acc[r][c] = 0.f;

    for (int k0 = 0; k0 < K; k0 += 16) {
        float4 a0 = {0,0,0,0}, a1 = {0,0,0,0};
        if (m0 + srow < M) {
            const float* p = Amat + (size_t)(m0 + srow) * lda + k0 + scol;
            a0 = *(const float4*)p; a1 = *(const float4*)(p + 4);
        }
        float4 b0 = {0,0,0,0}, b1 = {0,0,0,0};
        if (n0 + srow < N) {
            const float* p = Bmat + (size_t)(n0 + srow) * ldb + k0 + scol;
            b0 = *(const float4*)p; b1 = *(const float4*)(p + 4);
        }
        __syncthreads();
        As[scol + 0][srow] = a0.x; As[scol + 1][srow] = a0.y;
        As[scol + 2][srow] = a0.z; As[scol + 3][srow] = a0.w;
        As[scol + 4][srow] = a1.x; As[scol + 5][srow] = a1.y;
        As[scol + 6][srow] = a1.z; As[scol + 7][srow] = a1.w;
        Bs[scol + 0][srow] = b0.x; Bs[scol + 1][srow] = b0.y;
        Bs[scol + 2][srow] = b0.z; Bs[scol + 3][srow] = b0.w;
        Bs[scol + 4][srow] = b1.x; Bs[scol + 5][srow] = b1.y;
        Bs[scol + 6][srow] = b1.z; Bs[scol + 7][srow] = b1.w;
        __syncthreads();
        #pragma unroll
        for (int kk = 0; kk < 16; ++kk) {
            const float4 aL = *(const float4*)&As[kk][ty * 4];
            const float4 aH = *(const float4*)&As[kk][64 + ty * 4];
            const float4 bL = *(const float4*)&Bs[kk][tx * 4];
            const float4 bH = *(const float4*)&Bs[kk][64 + tx * 4];
            const float aa[8] = {aL.x, aL.y, aL.z, aL.w, aH.x, aH.y, aH.z, aH.w};
            const float bb[8] = {bL.x, bL.y, bL.z, bL.w, bH.x, bH.y, bH.z, bH.w};
            #pragma unroll
            for (int r = 0; r < 8; ++r)
                #pragma unroll
                for (int c = 0; c < 8; ++c) acc[r][c] += aa[r] * bb[c];
        }
    }

    #pragma unroll
    for (int r = 0; r < 8; ++r) {
        const int m = m0 + ((r < 4) ? (ty * 4 + r) : (64 + ty * 4 + r - 4));
        if (m >= M) continue;
        const float bm = (bm1 ? bm1[m] : 0.f) + (bm2 ? bm2[m] : 0.f);
        #pragma unroll
        for (int h = 0; h < 2; ++h) {
            const int n = n0 + h * 64 + tx * 4;
            if (n + 3 < N) {
                float4 o;
                o.x = acc[r][h*4+0] + bm + (bnv ? bnv[n+0] : 0.f);
                o.y = acc[r][h*4+1] + bm + (bnv ? bnv[n+1] : 0.f);
                o.z = acc[r][h*4+2] + bm + (bnv ? bnv[n+2] : 0.f);
                o.w = acc[r][h*4+3] + bm + (bnv ? bnv[n+3] : 0.f);
                *(float4*)&C[(size_t)m * ldc + n] = o;
            } else {
                #pragma unroll
                for (int c = 0; c < 4; ++c)
                    if (n + c < N)
                        C[(size_t)m * ldc + n + c] = acc[r][h*4+c] + bm + (bnv ? bnv[n+c] : 0.f);
            }
        }
    }
}

// ---------------- fp32 GEMM (B col-ish [k][n]): C[m][n] = sum_k A[m][k]*B[k][n]
__global__ __launch_bounds__(256) void gemm_nn_kernel(
    int M, int N, int K,
    const float* __restrict__ Amat, int lda,
    const float* __restrict__ Bmat, int ldb,   // B element [k][n] at Bmat[k*ldb+n]
    float* __restrict__ C, int ldc)
{
    __shared__ float As[16][128];
    __shared__ float Bs[16][128];
    const int tid = threadIdx.x;
    const int m0 = blockIdx.y * 128;
    const int n0 = blockIdx.x * 128;
    const int ty = tid >> 4, tx = tid & 15;
    const int srow = tid >> 1, scol = (tid & 1) * 8;
    const int bkk = tid >> 4, bnn = (tid & 15) * 8;

    float acc[8][8];
    #pragma unroll
    for (int r = 0; r < 8; ++r)
        #pragma unroll
        for (int c = 0; c < 8; ++c) acc[r][c] = 0.f;

    for (int k0 = 0; k0 < K; k0 += 16) {
        float4 a0 = {0,0,0,0}, a1 = {0,0,0,0};
        if (m0 + srow < M) {
            const float* p = Amat + (size_t)(m0 + srow) * lda + k0 + scol;
            a0 = *(const float4*)p; a1 = *(const float4*)(p + 4);
        }
        float4 b0 = {0,0,0,0}, b1 = {0,0,0,0};
        if (n0 + bnn + 7 < N) {
            const float* p = Bmat + (size_t)(k0 + bkk) * ldb + n0 + bnn;
            b0 = *(const float4*)p; b1 = *(const float4*)(p + 4);
        }
        __syncthreads();
        As[scol + 0][srow] = a0.x; As[scol + 1][srow] = a0.y;
        As[scol + 2][srow] = a0.z; As[scol + 3][srow] = a0.w;
        As[scol + 4][srow] = a1.x; As[scol + 5][srow] = a1.y;
        As[scol + 6][srow] = a1.z; As[scol + 7][srow] = a1.w;
        *(float4*)&Bs[bkk][bnn]     = b0;
        *(float4*)&Bs[bkk][bnn + 4] = b1;
        __syncthreads();
        #pragma unroll
        for (int kk = 0; kk < 16; ++kk) {
            const float4 aL = *(const float4*)&As[kk][ty * 4];
            const float4 aH = *(const float4*)&As[kk][64 + ty * 4];
            const float4 bL = *(const float4*)&Bs[kk][tx * 4];
            const float4 bH = *(const float4*)&Bs[kk][64 + tx * 4];
            const float aa[8] = {aL.x, aL.y, aL.z, aL.w, aH.x, aH.y, aH.z, aH.w};
            const float bb[8] = {bL.x, bL.y, bL.z, bL.w, bH.x, bH.y, bH.z, bH.w};
            #pragma unroll
            for (int r = 0; r < 8; ++r)
                #pragma unroll
                for (int c = 0; c < 8; ++c) acc[r][c] += aa[r] * bb[c];
        }
    }

    #pragma unroll
    for (int r = 0; r < 8; ++r) {
        const int m = m0 + ((r < 4) ? (ty * 4 + r) : (64 + ty * 4 + r - 4));
        if (m >= M) continue;
        #pragma unroll
        for (int h = 0; h < 2; ++h) {
            const int n = n0 + h * 64 + tx * 4;
            if (n + 3 < N) {
                float4 o = {acc[r][h*4+0], acc[r][h*4+1], acc[r][h*4+2], acc[r][h*4+3]};
                *(float4*)&C[(size_t)m * ldc + n] = o;
            }
        }
    }
}

// ---------------- persistent bidirectional LSTM ----------------
// 256 blocks = {dir(2)} x {u-quad(64)} x {b-half(2)}; block = 64 b x 4 u.
// h in global [dir][buf][k=256][b=128]: NT coalesced wave stores (same u,
// consecutive b), NT staged into LDS [k][64b] per step, then LDS reads
// hl[k*64+b] (2-way bank = free). Weights via wave-uniform scalar loads,
// L2-hot (no invalidation). Barriers per (dir, b-half): 64 members.
__global__ __launch_bounds__(256) void lstm_kernel(
    const float* __restrict__ Gf, const float* __restrict__ Gb,
    const float* __restrict__ Whh_f, const float* __restrict__ Whh_b,
    float* __restrict__ hT, float* __restrict__ lstm_out, int* cnt)
{
    __shared__ float hl[256 * 64];          // 64 KB
    const int blk = blockIdx.x;
    const int dir = blk >> 7;
    const int r   = blk & 127;
    const int u0  = (r >> 1) * 4;
    const int bh  = r & 1;
    const int b0  = bh * 64;
    const int tid = threadIdx.x;
    const int bl  = tid & 63;
    const int b   = b0 + bl;
    const int uh  = __builtin_amdgcn_readfirstlane(tid >> 6);
    const int u   = u0 + uh;
    const float* __restrict__ G   = dir ? Gb : Gf;
    const float* __restrict__ Whh = dir ? Whh_b : Whh_f;
    float* __restrict__ hTd = hT + (size_t)dir * (2 * HL * NB);
    const float* __restrict__ w0 = Whh + (size_t)(0 * HL + u) * HL;
    const float* __restrict__ w1 = Whh + (size_t)(1 * HL + u) * HL;
    const float* __restrict__ w2 = Whh + (size_t)(2 * HL + u) * HL;
    const float* __restrict__ w3 = Whh + (size_t)(3 * HL + u) * HL;
    const float* __restrict__ g0 = G + (size_t)(0 * HL + u) * 3200;
    const float* __restrict__ g1 = G + (size_t)(1 * HL + u) * 3200;
    const float* __restrict__ g2 = G + (size_t)(2 * HL + u) * 3200;
    const float* __restrict__ g3 = G + (size_t)(3 * HL + u) * 3200;
    int* mycnt = cnt + (dir * 2 + bh) * 16;
    const int kb = uh * 64 + (bl >> 4);     // staging k-base (wave stages 64 rows)
    const int b4 = (bl & 15) * 4;

    float c = 0.f;
    for (int s = 0; s < NT; ++s) {
        const int t  = dir ? (NT - 1 - s) : s;
        const int wb = s & 1, rb = wb ^ 1;
        const int col = t * NB + b;
        const float p0 = g0[col], p1 = g1[col], p2 = g2[col], p3 = g3[col];
        float a0 = 0.f, a1 = 0.f, a2 = 0.f, a3 = 0.f;
        if (s) {
            const float* hsrc = hTd + (size_t)rb * (HL * NB) + b0 + b4;
            #pragma unroll
            for (int i = 0; i < 16; ++i) {
                const int k = kb + i * 4;
                const v4f v = __builtin_nontemporal_load((const v4f*)(hsrc + (size_t)k * NB));
                *(v4f*)&hl[k * 64 + b4] = v;
            }
            __syncthreads();
            #pragma unroll 8
            for (int k = 0; k < HL; ++k) {
                const float hv = hl[k * 64 + bl];
                a0 = fmaf(w0[k], hv, a0);
                a1 = fmaf(w1[k], hv, a1);
                a2 = fmaf(w2[k], hv, a2);
                a3 = fmaf(w3[k], hv, a3);
            }
        }
        const float gi = sigm(a0 + p0);
        const float gf = sigm(a1 + p1);
        const float gg = tanhf(a2 + p2);
        const float go = sigm(a3 + p3);
        c = gf * c + gi * gg;
        const float h = go * tanhf(c);
        __builtin_nontemporal_store(h, hTd + (size_t)wb * (HL * NB) + (size_t)u * NB + b);
        __builtin_nontemporal_store(h, lstm_out + (size_t)(dir * HL + u) * 3200 + t * NB + b);
        if (s < NT - 1) gridbar(mycnt, 64 * (s + 1));
    }
}

// ---------------- persistent GRU decoder ----------------
// 256 blocks = {u-quad(128)} x {b-half(2)}; block = 64 b x 4 u.
// h global [buf][k=512][b=128], NT everywhere; LDS stage 128 KB (1 block/CU).
// Barriers per b-half: 128 members.
__global__ __launch_bounds__(256) void gru_kernel(
    const float* __restrict__ Gx, const float* __restrict__ embtab,
    const int* __restrict__ text, const float* __restrict__ Whh,
    const float* __restrict__ bhh, float* __restrict__ hgT,
    float* __restrict__ gru_out, int* cnt)
{
    __shared__ float hl[512 * 64];          // 128 KB
    const int blk = blockIdx.x;
    const int u0  = (blk >> 1) * 4;
    const int bh  = blk & 1;
    const int b0  = bh * 64;
    const int tid = threadIdx.x;
    const int bl  = tid & 63;
    const int b   = b0 + bl;
    const int uh  = __builtin_amdgcn_readfirstlane(tid >> 6);
    const int u   = u0 + uh;
    const float* __restrict__ wr = Whh + (size_t)(0 * 512 + u) * 512;
    const float* __restrict__ wz = Whh + (size_t)(1 * 512 + u) * 512;
    const float* __restrict__ wn = Whh + (size_t)(2 * 512 + u) * 512;
    const float* __restrict__ gr = Gx + (size_t)(0 * 512 + u) * 3200;
    const float* __restrict__ gz = Gx + (size_t)(1 * 512 + u) * 3200;
    const float* __restrict__ gn = Gx + (size_t)(2 * 512 + u) * 3200;
    const float br = bhh[u], bz = bhh[512 + u], bn_ = bhh[1024 + u];
    int* mycnt = cnt + (4 + bh) * 16;
    const int kb = uh * 128 + (bl >> 4);    // staging k-base (wave stages 128 rows)
    const int b4 = (bl & 15) * 4;

    float h = 0.f;
    for (int t = 0; t < NT; ++t) {
        const int wb = t & 1, rb = wb ^ 1;
        const int col = t * NB + b;
        const float pr = gr[col], pz = gz[col], pn = gn[col];
        const int tok = t ? text[b * NT + t - 1] : 0;
        const float* __restrict__ et = embtab + (size_t)tok * 1536;
        const float er = et[u], ez = et[512 + u], en = et[1024 + u];
        float ar = 0.f, az = 0.f, an = 0.f;
        if (t) {
            const float* hsrc = hgT + (size_t)rb * (512 * NB) + b0 + b4;
            #pragma unroll
            for (int i = 0; i < 32; ++i) {
                const int k = kb + i * 4;
                const v4f v = __builtin_nontemporal_load((const v4f*)(hsrc + (size_t)k * NB));
                *(v4f*)&hl[k * 64 + b4] = v;
            }
            __syncthreads();
            #pragma unroll 8
            for (int k = 0; k < 512; ++k) {
                const float hv = hl[k * 64 + bl];
                ar = fmaf(wr[k], hv, ar);
                az = fmaf(wz[k], hv, az);
                an = fmaf(wn[k], hv, an);
            }
        }
        const float rg = sigm(pr + er + ar + br);
        const float z  = sigm(pz + ez + az + bz);
        const float n  = tanhf(pn + en + rg * (an + bn_));
        h = (1.f - z) * n + z * h;
        __builtin_nontemporal_store(h, hgT + (size_t)wb * (512 * NB) + (size_t)u * NB + b);
        __builtin_nontemporal_store(h, gru_out + ((size_t)t * 512 + u) * NB + b);
        if (t < NT - 1) gridbar(mycnt, 128 * (t + 1));
    }
}

// ---------------- generator + ragged gather ----------------
// gru_out is [t][u][b]; stage x[u] cooperatively into LDS.
__global__ __launch_bounds__(64) void gen_gather_kernel(
    const float* __restrict__ gru_out, const float* __restrict__ Wg,
    const float* __restrict__ bg, const float* __restrict__ An,
    const int* __restrict__ pfx, const int* __restrict__ tlen,
    float* __restrict__ out)
{
    const int b = blockIdx.x / NT;
    const int t = blockIdx.x % NT;
    if (t >= tlen[b]) return;
    const int row = pfx[b] + t;
    const int L = pfx[NB];
    const int lane = threadIdx.x;

    __shared__ float xs[512];
    #pragma unroll
    for (int j = 0; j < 8; ++j)
        xs[lane + 64 * j] = gru_out[((size_t)t * 512 + lane + 64 * j) * NB + b];
    __syncthreads();

    if (lane < NCLS) {
        const float4* wrow = (const float4*)(Wg + (size_t)lane * 512);
        float acc = bg[lane];
        #pragma unroll 4
        for (int k4 = 0; k4 < 128; ++k4) {
            const float4 w = wrow[k4];
            const float4 xv = *(const float4*)&xs[k4 * 4];
            acc += w.x * xv.x + w.y * xv.y + w.z * xv.z + w.w * xv.w;
        }
        out[(size_t)row * NCLS + lane] = acc;
    }
    const float* an = An + ((size_t)b * NT + t) * NHW;
    float* oa = out + (size_t)L * NCLS + (size_t)row * NHW;
    for (int i = lane; i < NHW; i += 64) oa[i] = an[i];
}

// ---------------- launch ----------------
extern "C" void kernel_launch(void* const* d_in, const int* in_sizes, int n_in,
                              void* d_out, int out_size, void* d_ws, size_t ws_size,
                              hipStream_t stream)
{
    const float* feature = (const float*)d_in[0];
    const float* A       = (const float*)d_in[1];
    const int*   text    = (const int*)d_in[2];
    const int*   tlen    = (const int*)d_in[3];
    const float* W_ih_f  = (const float*)d_in[4];
    const float* W_hh_f  = (const float*)d_in[5];
    const float* b_ih_f  = (const float*)d_in[6];
    const float* b_hh_f  = (const float*)d_in[7];
    const float* W_ih_b  = (const float*)d_in[8];
    const float* W_hh_b  = (const float*)d_in[9];
    const float* b_ih_b  = (const float*)d_in[10];
    const float* b_hh_b  = (const float*)d_in[11];
    const float* W_ih_g  = (const float*)d_in[12];
    const float* W_hh_g  = (const float*)d_in[13];
    const float* b_ih_g  = (const float*)d_in[14];
    const float* b_hh_g  = (const float*)d_in[15];
    const float* W_gen   = (const float*)d_in[16];
    const float* b_gen   = (const float*)d_in[17];
    const float* cemb    = (const float*)d_in[18];

    float* ws       = (float*)d_ws;
    float* Anorm    = ws + OFF_ANORM;
    float* Cpool    = ws + OFF_CPOOL;
    float* hT       = ws + OFF_HT;      // aliases Cpool (dead by then)
    float* hgT      = ws + OFF_HGT;     // aliases Cpool
    float* Gf       = ws + OFF_GF;
    float* Gb       = ws + OFF_GB;
    float* Gx       = ws + OFF_GX;      // aliases Gf/Gb (dead by then)
    float* lstm_out = ws + OFF_LSTMOUT;
    float* gru_out  = ws + OFF_GRUOUT;  // aliases lstm_out (dead by then)
    float* embtab   = ws + OFF_EMBTAB;
    int*   ip       = (int*)(ws + OFF_INT);
    int*   cnt      = ip;               // 64B-padded: lstm (dir*2+bh)*16, gru (4+bh)*16
    int*   pfx      = ip + 128;

    (void)hipMemsetAsync(cnt, 0, 96 * sizeof(int), stream);

    prefix_kernel<<<1, 64, 0, stream>>>(tlen, pfx);
    norm_attn_kernel<<<NB * NT, 256, 0, stream>>>(A, Anorm);
    pool_kernel<<<dim3(2, NB), 256, 0, stream>>>(feature, Anorm, Cpool);

    // LSTM input gates: G'[row(1024)][t*128+b]
    gemm_tn_kernel<<<dim3(25, 8), 256, 0, stream>>>(1024, 3200, 512,
        W_ih_f, 512, Cpool, 512, b_ih_f, b_hh_f, nullptr, Gf, 3200);
    gemm_tn_kernel<<<dim3(25, 8), 256, 0, stream>>>(1024, 3200, 512,
        W_ih_b, 512, Cpool, 512, b_ih_b, b_hh_b, nullptr, Gb, 3200);
    // emb table: embtab[tok][row] = cemb @ W_ih_g[:,512:]^T + b_ih_g
    gemm_tn_kernel<<<dim3(12, 1), 256, 0, stream>>>(38, 1536, 512,
        cemb, 512, W_ih_g + 512, 1024, nullptr, nullptr, b_ih_g, embtab, 1536);

    lstm_kernel<<<256, 256, 0, stream>>>(Gf, Gb, W_hh_f, W_hh_b, hT, lstm_out, cnt);

    // GRU input gates from transposed lstm_out [k=ch][n=t*128+b]
    gemm_nn_kernel<<<dim3(25, 12), 256, 0, stream>>>(1536, 3200, 512,
        W_ih_g, 1024, lstm_out, 3200, Gx, 3200);

    gru_kernel<<<256, 256, 0, stream>>>(Gx, embtab, text, W_hh_g, b_hh_g, hgT, gru_out, cnt);

    gen_gather_kernel<<<NB * NT, 64, 0, stream>>>(gru_out, W_gen, b_gen, Anorm, pfx, tlen, (float*)d_out);
}

// Round 11
// 1227.131 us; speedup vs baseline: 1.9075x; 1.4578x over previous
//
#include <hip/hip_runtime.h>
#include <math.h>

// Problem constants
#define NB   128
#define NT   25
#define NCH  512
#define HL   256      // LSTM hidden per direction
#define NHW  256      // 8*32
#define NCLS 38

typedef float v4f __attribute__((ext_vector_type(4)));  // native vec for NT builtins

// ---------------- workspace layout (float offsets) ----------------
#define OFF_ANORM   0u
#define SZ_ANORM    (128u*25u*256u)              // 819200
#define OFF_CPOOL   (OFF_ANORM + SZ_ANORM)       // 819200
#define SZ_CPOOL    (25u*128u*512u)              // 1638400
#define OFF_HT      OFF_CPOOL                    // alias: 2dir*2buf*[256k][128b] = 131072
#define OFF_HGT     (OFF_CPOOL + 131072u)        // alias: 2buf*[512k][128b]      = 131072
#define OFF_G       (OFF_CPOOL + SZ_CPOOL)       // 2457600
#define SZ_GF       (1024u*3200u)                // 3276800
#define OFF_GF      OFF_G
#define OFF_GB      (OFF_G + SZ_GF)
#define OFF_GX      OFF_G                        // alias: 1536*3200 <= 2*SZ_GF
#define OFF_LSTMOUT (OFF_G + 2u*SZ_GF)           // 9011200: [512ch][3200]
#define SZ_LSTMOUT  (25u*128u*512u)              // 1638400
#define OFF_GRUOUT  OFF_LSTMOUT                  // alias: [25t][512u][128b]
#define OFF_EMBTAB  (OFF_LSTMOUT + SZ_LSTMOUT)   // 10649600
#define SZ_EMBTAB   (38u*1536u)                  // 58368
#define OFF_INT     (OFF_EMBTAB + SZ_EMBTAB)     // 10707968
// int area layout (ip = int*):
//   ip[0..63]    : epochs, one per 64B: LSTM groups g=0..3 at 16*g; GRU g at 64+16*g
//   ip[128..383] : LSTM flags, 4 groups x 64 members
//   ip[384..639] : GRU flags, 2 groups x 128 members
//   ip[640..768] : prefix sums

__device__ __forceinline__ float sigm(float x) { return 1.0f / (1.0f + expf(-x)); }

// ---------------- flag/epoch grid barrier (no RMW, no release/acquire) ------
// Memory model established r6/r8 on gfx950:
//   * NT stores stay dirty in producer-XCD L2 (NOT agent-visible) -> h values
//     are published with per-element agent-scope relaxed ATOMIC stores
//     (write-through to L3, the coherence point). No cache-wide release walk.
//   * NT loads read fresh past L2 (r6 passed 24 dependent steps w/o acquire).
// Protocol per step: all h-stores drained by __syncthreads (vmcnt 0); leader
// writes its member flag (write-through). Aggregator wave (member 0) ballots
// all member flags, publishes epoch; members poll epoch read-only. Flags are
// monotonic step counters -> no reset, no ABA.
__device__ __forceinline__ void flagbar(int* fl, int* ep, int q, int nm, int target) {
    __syncthreads();                     // h-store drain precedes flag store
    const int tid = threadIdx.x;
    if (tid == 0)
        __hip_atomic_store(fl + q, target, __ATOMIC_RELAXED, __HIP_MEMORY_SCOPE_AGENT);
    if (q == 0) {
        if (tid < 64) {
            for (;;) {
                bool ok = true;
                for (int i = tid; i < nm; i += 64)
                    ok = ok && (__hip_atomic_load(fl + i, __ATOMIC_RELAXED,
                                                  __HIP_MEMORY_SCOPE_AGENT) >= target);
                if (__all(ok)) break;
                __builtin_amdgcn_s_sleep(4);
            }
            if (tid == 0)
                __hip_atomic_store(ep, target, __ATOMIC_RELAXED, __HIP_MEMORY_SCOPE_AGENT);
        }
    } else if (tid == 0) {
        while (__hip_atomic_load(ep, __ATOMIC_RELAXED, __HIP_MEMORY_SCOPE_AGENT) < target)
            __builtin_amdgcn_s_sleep(4);
    }
    __syncthreads();
}

// ---------------- prefix sums of text_length ----------------
__global__ void prefix_kernel(const int* __restrict__ tlen, int* __restrict__ pfx) {
    if (threadIdx.x == 0) {
        int s = 0;
        for (int i = 0; i < NB; ++i) { pfx[i] = s; s += tlen[i]; }
        pfx[NB] = s;
    }
}

// ---------------- normalize attention maps per (b,t) ----------------
__global__ __launch_bounds__(256) void norm_attn_kernel(const float* __restrict__ A,
                                                        float* __restrict__ An) {
    const int bt = blockIdx.x;             // b*25 + t
    const int tid = threadIdx.x;
    float v = A[(size_t)bt * NHW + tid];
    float s = v;
    #pragma unroll
    for (int off = 32; off > 0; off >>= 1) s += __shfl_down(s, off, 64);
    __shared__ float wsum[4];
    if ((tid & 63) == 0) wsum[tid >> 6] = s;
    __syncthreads();
    float tot = wsum[0] + wsum[1] + wsum[2] + wsum[3];
    An[(size_t)bt * NHW + tid] = v / tot;
}

// ---------------- attention pooling: Cpool[t][b][c] = sum_hw feat[b][c][hw]*An[b][t][hw]
__global__ __launch_bounds__(256) void pool_kernel(const float* __restrict__ feature,
                                                   const float* __restrict__ An,
                                                   float* __restrict__ Cpool) {
    __shared__ float al[25][256];
    const int b = blockIdx.y;
    const int c = blockIdx.x * 256 + threadIdx.x;
    for (int i = threadIdx.x; i < 25 * 256; i += 256)
        al[i >> 8][i & 255] = An[(size_t)b * 25 * 256 + i];
    __syncthreads();
    const float* f = feature + ((size_t)b * NCH + c) * NHW;
    float acc[25];
    #pragma unroll
    for (int t = 0; t < 25; ++t) acc[t] = 0.f;
    for (int hw = 0; hw < NHW; hw += 4) {
        const float4 fv = *(const float4*)(f + hw);
        #pragma unroll
        for (int t = 0; t < 25; ++t) {
            const float4 av = *(const float4*)&al[t][hw];
            acc[t] += fv.x * av.x + fv.y * av.y + fv.z * av.z + fv.w * av.w;
        }
    }
    #pragma unroll
    for (int t = 0; t < 25; ++t)
        Cpool[((size_t)t * NB + b) * NCH + c] = acc[t];
}

// ---------------- fp32 GEMM (B row-major [n][k]): C[m][n] = sum_k A[m][k]*B[n][k]
__global__ __launch_bounds__(256) void gemm_tn_kernel(
    int M, int N, int K,
    const float* __restrict__ Amat, int lda,
    const float* __restrict__ Bmat, int ldb,
    const float* __restrict__ bm1, const float* __restrict__ bm2,
    const float* __restrict__ bnv,
    float* __restrict__ C, int ldc)
{
    __shared__ float As[16][128];
    __shared__ float Bs[16][128];
    const int tid = threadIdx.x;
    const int m0 = blockIdx.y * 128;
    const int n0 = blockIdx.x * 128;
    const int ty = tid >> 4, tx = tid & 15;
    const int srow = tid >> 1, scol = (tid & 1) * 8;

    float acc[8][8];
    #pragma unroll
    for (int r = 0; r < 8; ++r)
        #pragma unroll
        for (int c = 0; c < 8; ++c) acc[r][c] = 0.f;

    for (int k0 = 0; k0 < K; k0 += 16) {
        float4 a0 = {0,0,0,0}, a1 = {0,0,0,0};
        if (m0 + srow < M) {
            const float* p = Amat + (size_t)(m0 + srow) * lda + k0 + scol;
            a0 = *(const float4*)p; a1 = *(const float4*)(p + 4);
        }
        float4 b0 = {0,0,0,0}, b1 = {0,0,0,0};
        if (n0 + srow < N) {
            const float* p = Bmat + (size_t)(n0 + srow) * ldb + k0 + scol;
            b0 = *(const float4*)p; b1 = *(const float4*)(p + 4);
        }
        __syncthreads();
        As[scol + 0][srow] = a0.x; As[scol + 1][srow] = a0.y;
        As[scol + 2][srow] = a0.z; As[scol + 3][srow] = a0.w;
        As[scol + 4][srow] = a1.x; As[scol + 5][srow] = a1.y;
        As[scol + 6][srow] = a1.z; As[scol + 7][srow] = a1.w;
        Bs[scol + 0][srow] = b0.x; Bs[scol + 1][srow] = b0.y;
        Bs[scol + 2][srow] = b0.z; Bs[scol + 3][srow] = b0.w;
        Bs[scol + 4][srow] = b1.x; Bs[scol + 5][srow] = b1.y;
        Bs[scol + 6][srow] = b1.z; Bs[scol + 7][srow] = b1.w;
        __syncthreads();
        #pragma unroll
        for (int kk = 0; kk < 16; ++kk) {
            const float4 aL = *(const float4*)&As[kk][ty * 4];
            const float4 aH = *(const float4*)&As[kk][64 + ty * 4];
            const float4 bL = *(const float4*)&Bs[kk][tx * 4];
            const float4 bH = *(const float4*)&Bs[kk][64 + tx * 4];
            const float aa[8] = {aL.x, aL.y, aL.z, aL.w, aH.x, aH.y, aH.z, aH.w};
            const float bb[8] = {bL.x, bL.y, bL.z, bL.w, bH.x, bH.y, bH.z, bH.w};
            #pragma unroll
            for (int r = 0; r < 8; ++r)
                #pragma unroll
                for (int c = 0; c < 8; ++c) acc[r][c] += aa[r] * bb[c];
        }
    }

    #pragma unroll
    for (int r = 0; r < 8; ++r) {
        const int m = m0 + ((r < 4) ? (ty * 4 + r) : (64 + ty * 4 + r - 4));
        if (m >= M) continue;
        const float bm = (bm1 ? bm1[m] : 0.f) + (bm2 ? bm2[m] : 0.f);
        #pragma unroll
        for (int h = 0; h < 2; ++h) {
            const int n = n0 + h * 64 + tx * 4;
            if (n + 3 < N) {
                float4 o;
                o.x = acc[r][h*4+0] + bm + (bnv ? bnv[n+0] : 0.f);
                o.y = acc[r][h*4+1] + bm + (bnv ? bnv[n+1] : 0.f);
                o.z = acc[r][h*4+2] + bm + (bnv ? bnv[n+2] : 0.f);
                o.w = acc[r][h*4+3] + bm + (bnv ? bnv[n+3] : 0.f);
                *(float4*)&C[(size_t)m * ldc + n] = o;
            } else {
                #pragma unroll
                for (int c = 0; c < 4; ++c)
                    if (n + c < N)
                        C[(size_t)m * ldc + n + c] = acc[r][h*4+c] + bm + (bnv ? bnv[n+c] : 0.f);
            }
        }
    }
}

// ---------------- fp32 GEMM (B col-ish [k][n]): C[m][n] = sum_k A[m][k]*B[k][n]
__global__ __launch_bounds__(256) void gemm_nn_kernel(
    int M, int N, int K,
    const float* __restrict__ Amat, int lda,
    const float* __restrict__ Bmat, int ldb,   // B element [k][n] at Bmat[k*ldb+n]
    float* __restrict__ C, int ldc)
{
    __shared__ float As[16][128];
    __shared__ float Bs[16][128];
    const int tid = threadIdx.x;
    const int m0 = blockIdx.y * 128;
    const int n0 = blockIdx.x * 128;
    const int ty = tid >> 4, tx = tid & 15;
    const int srow = tid >> 1, scol = (tid & 1) * 8;
    const int bkk = tid >> 4, bnn = (tid & 15) * 8;

    float acc[8][8];
    #pragma unroll
    for (int r = 0; r < 8; ++r)
        #pragma unroll
        for (int c = 0; c < 8; ++c) acc[r][c] = 0.f;

    for (int k0 = 0; k0 < K; k0 += 16) {
        float4 a0 = {0,0,0,0}, a1 = {0,0,0,0};
        if (m0 + srow < M) {
            const float* p = Amat + (size_t)(m0 + srow) * lda + k0 + scol;
            a0 = *(const float4*)p; a1 = *(const float4*)(p + 4);
        }
        float4 b0 = {0,0,0,0}, b1 = {0,0,0,0};
        if (n0 + bnn + 7 < N) {
            const float* p = Bmat + (size_t)(k0 + bkk) * ldb + n0 + bnn;
            b0 = *(const float4*)p; b1 = *(const float4*)(p + 4);
        }
        __syncthreads();
        As[scol + 0][srow] = a0.x; As[scol + 1][srow] = a0.y;
        As[scol + 2][srow] = a0.z; As[scol + 3][srow] = a0.w;
        As[scol + 4][srow] = a1.x; As[scol + 5][srow] = a1.y;
        As[scol + 6][srow] = a1.z; As[scol + 7][srow] = a1.w;
        *(float4*)&Bs[bkk][bnn]     = b0;
        *(float4*)&Bs[bkk][bnn + 4] = b1;
        __syncthreads();
        #pragma unroll
        for (int kk = 0; kk < 16; ++kk) {
            const float4 aL = *(const float4*)&As[kk][ty * 4];
            const float4 aH = *(const float4*)&As[kk][64 + ty * 4];
            const float4 bL = *(const float4*)&Bs[kk][tx * 4];
            const float4 bH = *(const float4*)&Bs[kk][64 + tx * 4];
            const float aa[8] = {aL.x, aL.y, aL.z, aL.w, aH.x, aH.y, aH.z, aH.w};
            const float bb[8] = {bL.x, bL.y, bL.z, bL.w, bH.x, bH.y, bH.z, bH.w};
            #pragma unroll
            for (int r = 0; r < 8; ++r)
                #pragma unroll
                for (int c = 0; c < 8; ++c) acc[r][c] += aa[r] * bb[c];
        }
    }

    #pragma unroll
    for (int r = 0; r < 8; ++r) {
        const int m = m0 + ((r < 4) ? (ty * 4 + r) : (64 + ty * 4 + r - 4));
        if (m >= M) continue;
        #pragma unroll
        for (int h = 0; h < 2; ++h) {
            const int n = n0 + h * 64 + tx * 4;
            if (n + 3 < N) {
                float4 o = {acc[r][h*4+0], acc[r][h*4+1], acc[r][h*4+2], acc[r][h*4+3]};
                *(float4*)&C[(size_t)m * ldc + n] = o;
            }
        }
    }
}

// ---------------- persistent bidirectional LSTM ----------------
// 256 blocks = {dir(2)} x {u-quad(64)} x {b-half(2)}; block = 64 b x 4 u.
// h published via agent-scope atomic stores (write-through to L3); staged
// back via NT vector loads (L2-bypassing reads, r6-proven). Weights stay
// L2-hot. Barrier: flagbar per (dir,bh) group of 64, member q = u-quad.
__global__ __launch_bounds__(256) void lstm_kernel(
    const float* __restrict__ Gf, const float* __restrict__ Gb,
    const float* __restrict__ Whh_f, const float* __restrict__ Whh_b,
    float* __restrict__ hT, float* __restrict__ lstm_out, int* ip)
{
    __shared__ float hl[256 * 64];          // 64 KB
    const int blk = blockIdx.x;
    const int dir = blk >> 7;
    const int r   = blk & 127;
    const int q   = r >> 1;                 // member index in group
    const int u0  = q * 4;
    const int bh  = r & 1;
    const int b0  = bh * 64;
    const int g   = dir * 2 + bh;           // barrier group
    const int tid = threadIdx.x;
    const int bl  = tid & 63;
    const int b   = b0 + bl;
    const int uh  = __builtin_amdgcn_readfirstlane(tid >> 6);
    const int u   = u0 + uh;
    const float* __restrict__ G   = dir ? Gb : Gf;
    const float* __restrict__ Whh = dir ? Whh_b : Whh_f;
    float* __restrict__ hTd = hT + (size_t)dir * (2 * HL * NB);
    const float* __restrict__ w0 = Whh + (size_t)(0 * HL + u) * HL;
    const float* __restrict__ w1 = Whh + (size_t)(1 * HL + u) * HL;
    const float* __restrict__ w2 = Whh + (size_t)(2 * HL + u) * HL;
    const float* __restrict__ w3 = Whh + (size_t)(3 * HL + u) * HL;
    const float* __restrict__ g0 = G + (size_t)(0 * HL + u) * 3200;
    const float* __restrict__ g1 = G + (size_t)(1 * HL + u) * 3200;
    const float* __restrict__ g2 = G + (size_t)(2 * HL + u) * 3200;
    const float* __restrict__ g3 = G + (size_t)(3 * HL + u) * 3200;
    int* fl = ip + 128 + g * 64;
    int* ep = ip + g * 16;
    const int kb = uh * 64 + (bl >> 4);     // staging k-base (wave stages 64 rows)
    const int b4 = (bl & 15) * 4;

    float c = 0.f;
    for (int s = 0; s < NT; ++s) {
        const int t  = dir ? (NT - 1 - s) : s;
        const int wb = s & 1, rb = wb ^ 1;
        const int col = t * NB + b;
        const float p0 = g0[col], p1 = g1[col], p2 = g2[col], p3 = g3[col];
        float a0 = 0.f, a1 = 0.f, a2 = 0.f, a3 = 0.f;
        if (s) {
            const float* hsrc = hTd + (size_t)rb * (HL * NB) + b0 + b4;
            #pragma unroll
            for (int i = 0; i < 16; ++i) {
                const int k = kb + i * 4;
                const v4f v = __builtin_nontemporal_load((const v4f*)(hsrc + (size_t)k * NB));
                *(v4f*)&hl[k * 64 + b4] = v;
            }
            __syncthreads();
            #pragma unroll 8
            for (int k = 0; k < HL; ++k) {
                const float hv = hl[k * 64 + bl];
                a0 = fmaf(w0[k], hv, a0);
                a1 = fmaf(w1[k], hv, a1);
                a2 = fmaf(w2[k], hv, a2);
                a3 = fmaf(w3[k], hv, a3);
            }
        }
        const float gi = sigm(a0 + p0);
        const float gf = sigm(a1 + p1);
        const float gg = tanhf(a2 + p2);
        const float go = sigm(a3 + p3);
        c = gf * c + gi * gg;
        const float h = go * tanhf(c);
        // agent-visible write-through publish of h (the r8 fix)
        __hip_atomic_store(hTd + (size_t)wb * (HL * NB) + (size_t)u * NB + b, h,
                           __ATOMIC_RELAXED, __HIP_MEMORY_SCOPE_AGENT);
        __builtin_nontemporal_store(h, lstm_out + (size_t)(dir * HL + u) * 3200 + t * NB + b);
        if (s < NT - 1) flagbar(fl, ep, q, 64, s + 1);
    }
}

// ---------------- persistent GRU decoder ----------------
// 256 blocks = {u-quad(128)} x {b-half(2)}; block = 64 b x 4 u.
// Same publish/stage scheme; barrier groups per bh: 128 members.
__global__ __launch_bounds__(256) void gru_kernel(
    const float* __restrict__ Gx, const float* __restrict__ embtab,
    const int* __restrict__ text, const float* __restrict__ Whh,
    const float* __restrict__ bhh, float* __restrict__ hgT,
    float* __restrict__ gru_out, int* ip)
{
    __shared__ float hl[512 * 64];          // 128 KB
    const int blk = blockIdx.x;
    const int q   = blk >> 1;               // member index in group
    const int u0  = q * 4;
    const int bh  = blk & 1;
    const int b0  = bh * 64;
    const int tid = threadIdx.x;
    const int bl  = tid & 63;
    const int b   = b0 + bl;
    const int uh  = __builtin_amdgcn_readfirstlane(tid >> 6);
    const int u   = u0 + uh;
    const float* __restrict__ wr = Whh + (size_t)(0 * 512 + u) * 512;
    const float* __restrict__ wz = Whh + (size_t)(1 * 512 + u) * 512;
    const float* __restrict__ wn = Whh + (size_t)(2 * 512 + u) * 512;
    const float* __restrict__ gr = Gx + (size_t)(0 * 512 + u) * 3200;
    const float* __restrict__ gz = Gx + (size_t)(1 * 512 + u) * 3200;
    const float* __restrict__ gn = Gx + (size_t)(2 * 512 + u) * 3200;
    const float br = bhh[u], bz = bhh[512 + u], bn_ = bhh[1024 + u];
    int* fl = ip + 384 + bh * 128;
    int* ep = ip + (4 + bh) * 16;
    const int kb = uh * 128 + (bl >> 4);    // staging k-base (wave stages 128 rows)
    const int b4 = (bl & 15) * 4;

    float h = 0.f;
    for (int t = 0; t < NT; ++t) {
        const int wb = t & 1, rb = wb ^ 1;
        const int col = t * NB + b;
        const float pr = gr[col], pz = gz[col], pn = gn[col];
        const int tok = t ? text[b * NT + t - 1] : 0;
        const float* __restrict__ et = embtab + (size_t)tok * 1536;
        const float er = et[u], ez = et[512 + u], en = et[1024 + u];
        float ar = 0.f, az = 0.f, an = 0.f;
        if (t) {
            const float* hsrc = hgT + (size_t)rb * (512 * NB) + b0 + b4;
            #pragma unroll
            for (int i = 0; i < 32; ++i) {
                const int k = kb + i * 4;
                const v4f v = __builtin_nontemporal_load((const v4f*)(hsrc + (size_t)k * NB));
                *(v4f*)&hl[k * 64 + b4] = v;
            }
            __syncthreads();
            #pragma unroll 8
            for (int k = 0; k < 512; ++k) {
                const float hv = hl[k * 64 + bl];
                ar = fmaf(wr[k], hv, ar);
                az = fmaf(wz[k], hv, az);
                an = fmaf(wn[k], hv, an);
            }
        }
        const float rg = sigm(pr + er + ar + br);
        const float z  = sigm(pz + ez + az + bz);
        const float n  = tanhf(pn + en + rg * (an + bn_));
        h = (1.f - z) * n + z * h;
        __hip_atomic_store(hgT + (size_t)wb * (512 * NB) + (size_t)u * NB + b, h,
                           __ATOMIC_RELAXED, __HIP_MEMORY_SCOPE_AGENT);
        __builtin_nontemporal_store(h, gru_out + ((size_t)t * 512 + u) * NB + b);
        if (t < NT - 1) flagbar(fl, ep, q, 128, t + 1);
    }
}

// ---------------- generator + ragged gather ----------------
// gru_out is [t][u][b]; stage x[u] cooperatively into LDS.
__global__ __launch_bounds__(64) void gen_gather_kernel(
    const float* __restrict__ gru_out, const float* __restrict__ Wg,
    const float* __restrict__ bg, const float* __restrict__ An,
    const int* __restrict__ pfx, const int* __restrict__ tlen,
    float* __restrict__ out)
{
    const int b = blockIdx.x / NT;
    const int t = blockIdx.x % NT;
    if (t >= tlen[b]) return;
    const int row = pfx[b] + t;
    const int L = pfx[NB];
    const int lane = threadIdx.x;

    __shared__ float xs[512];
    #pragma unroll
    for (int j = 0; j < 8; ++j)
        xs[lane + 64 * j] = gru_out[((size_t)t * 512 + lane + 64 * j) * NB + b];
    __syncthreads();

    if (lane < NCLS) {
        const float4* wrow = (const float4*)(Wg + (size_t)lane * 512);
        float acc = bg[lane];
        #pragma unroll 4
        for (int k4 = 0; k4 < 128; ++k4) {
            const float4 w = wrow[k4];
            const float4 xv = *(const float4*)&xs[k4 * 4];
            acc += w.x * xv.x + w.y * xv.y + w.z * xv.z + w.w * xv.w;
        }
        out[(size_t)row * NCLS + lane] = acc;
    }
    const float* an = An + ((size_t)b * NT + t) * NHW;
    float* oa = out + (size_t)L * NCLS + (size_t)row * NHW;
    for (int i = lane; i < NHW; i += 64) oa[i] = an[i];
}

// ---------------- launch ----------------
extern "C" void kernel_launch(void* const* d_in, const int* in_sizes, int n_in,
                              void* d_out, int out_size, void* d_ws, size_t ws_size,
                              hipStream_t stream)
{
    const float* feature = (const float*)d_in[0];
    const float* A       = (const float*)d_in[1];
    const int*   text    = (const int*)d_in[2];
    const int*   tlen    = (const int*)d_in[3];
    const float* W_ih_f  = (const float*)d_in[4];
    const float* W_hh_f  = (const float*)d_in[5];
    const float* b_ih_f  = (const float*)d_in[6];
    const float* b_hh_f  = (const float*)d_in[7];
    const float* W_ih_b  = (const float*)d_in[8];
    const float* W_hh_b  = (const float*)d_in[9];
    const float* b_ih_b  = (const float*)d_in[10];
    const float* b_hh_b  = (const float*)d_in[11];
    const float* W_ih_g  = (const float*)d_in[12];
    const float* W_hh_g  = (const float*)d_in[13];
    const float* b_ih_g  = (const float*)d_in[14];
    const float* b_hh_g  = (const float*)d_in[15];
    const float* W_gen   = (const float*)d_in[16];
    const float* b_gen   = (const float*)d_in[17];
    const float* cemb    = (const float*)d_in[18];

    float* ws       = (float*)d_ws;
    float* Anorm    = ws + OFF_ANORM;
    float* Cpool    = ws + OFF_CPOOL;
    float* hT       = ws + OFF_HT;      // aliases Cpool (dead by then)
    float* hgT      = ws + OFF_HGT;     // aliases Cpool
    float* Gf       = ws + OFF_GF;
    float* Gb       = ws + OFF_GB;
    float* Gx       = ws + OFF_GX;      // aliases Gf/Gb (dead by then)
    float* lstm_out = ws + OFF_LSTMOUT;
    float* gru_out  = ws + OFF_GRUOUT;  // aliases lstm_out (dead by then)
    float* embtab   = ws + OFF_EMBTAB;
    int*   ip       = (int*)(ws + OFF_INT);
    int*   pfx      = ip + 640;

    // zero epochs + flags (ip[0..639]); ws is poisoned 0xAA before every call
    (void)hipMemsetAsync(ip, 0, 640 * sizeof(int), stream);

    prefix_kernel<<<1, 64, 0, stream>>>(tlen, pfx);
    norm_attn_kernel<<<NB * NT, 256, 0, stream>>>(A, Anorm);
    pool_kernel<<<dim3(2, NB), 256, 0, stream>>>(feature, Anorm, Cpool);

    // LSTM input gates: G'[row(1024)][t*128+b]
    gemm_tn_kernel<<<dim3(25, 8), 256, 0, stream>>>(1024, 3200, 512,
        W_ih_f, 512, Cpool, 512, b_ih_f, b_hh_f, nullptr, Gf, 3200);
    gemm_tn_kernel<<<dim3(25, 8), 256, 0, stream>>>(1024, 3200, 512,
        W_ih_b, 512, Cpool, 512, b_ih_b, b_hh_b, nullptr, Gb, 3200);
    // emb table: embtab[tok][row] = cemb @ W_ih_g[:,512:]^T + b_ih_g
    gemm_tn_kernel<<<dim3(12, 1), 256, 0, stream>>>(38, 1536, 512,
        cemb, 512, W_ih_g + 512, 1024, nullptr, nullptr, b_ih_g, embtab, 1536);

    lstm_kernel<<<256, 256, 0, stream>>>(Gf, Gb, W_hh_f, W_hh_b, hT, lstm_out, ip);

    // GRU input gates from transposed lstm_out [k=ch][n=t*128+b]
    gemm_nn_kernel<<<dim3(25, 12), 256, 0, stream>>>(1536, 3200, 512,
        W_ih_g, 1024, lstm_out, 3200, Gx, 3200);

    gru_kernel<<<256, 256, 0, stream>>>(Gx, embtab, text, W_hh_g, b_hh_g, hgT, gru_out, ip);

    gen_gather_kernel<<<NB * NT, 64, 0, stream>>>(gru_out, W_gen, b_gen, Anorm, pfx, tlen, (float*)d_out);
}